// Round 4
// baseline (470.967 us; speedup 1.0000x reference)
//
#include <hip/hip_runtime.h>

#define NA 4096
#define NB 4096
#define DIM 256
#define DK 64
#define PSTR 72          // pbuf row stride (bf16 elements)
#define PBLK 1040        // partial block: 16*64 num + 16 den (floats)
// LDS union: pbuf needs 8*16*PSTR*2 = 18432 B; numbuf needs 8*16*65*4 = 33280 B.
// R3 bug was sizing this at 18432 -> numbuf overflow corrupted denbuf.
#define SMEM_BYTES 33280

typedef __attribute__((ext_vector_type(8))) short bf16x8;
typedef __attribute__((ext_vector_type(4))) float f32x4;
typedef __attribute__((ext_vector_type(4))) unsigned short us4;
typedef __attribute__((ext_vector_type(4))) int i32x4;

static __device__ __forceinline__ float bf2f(unsigned short u) {
    union { unsigned int u; float f; } x;
    x.u = ((unsigned int)u) << 16;
    return x.f;
}
static __device__ __forceinline__ unsigned short f2bf(float f) {
    union { float f; unsigned int u; } x;
    x.f = f;
    unsigned int r = x.u + 0x7fffu + ((x.u >> 16) & 1u);
    return (unsigned short)(r >> 16);
}

// ---------------------------------------------------------------------------
// Pre-split: fp32 -> bf16 hi + lo correction, fully coalesced elementwise.
// ---------------------------------------------------------------------------
__global__ __launch_bounds__(256) void split_kernel(
    const float* __restrict__ a_z, const float* __restrict__ bv_z,
    const float* __restrict__ Wq, const float* __restrict__ Wk,
    const float* __restrict__ Wv,
    unsigned short* __restrict__ ah, unsigned short* __restrict__ al,
    unsigned short* __restrict__ bh, unsigned short* __restrict__ bl,
    unsigned short* __restrict__ wparts)
{
    const int seg = blockIdx.y;
    const float* __restrict__ src;
    unsigned short *hi, *lo;
    int n;
    if (seg == 0)      { src = a_z;  hi = ah; lo = al; n = NA * DIM; }
    else if (seg == 1) { src = bv_z; hi = bh; lo = bl; n = NB * DIM; }
    else {
        src = (seg == 2) ? Wq : ((seg == 3) ? Wk : Wv);
        hi = wparts + (seg - 2) * 2 * DIM * DIM;
        lo = hi + DIM * DIM;
        n = DIM * DIM;
    }
    const int i = (blockIdx.x * 256 + threadIdx.x) * 4;
    if (i >= n) return;
    f32x4 v = *(const f32x4*)(src + i);
    us4 h4, l4;
    #pragma unroll
    for (int r = 0; r < 4; ++r) {
        unsigned short h = f2bf(v[r]);
        h4[r] = h;
        l4[r] = f2bf(v[r] - bf2f(h));
    }
    *(us4*)(hi + i) = h4;
    *(us4*)(lo + i) = l4;
}

// ---------------------------------------------------------------------------
// Projections from pre-split bf16, fp32-accurate via 3-term MFMA:
//   X·W^T ≈ xh·wh + xl·wh + xh·wl
// mat 0: q -> q_hi + q_lo ; mat 1: k -> k_hi ; mat 2: v -> vt (transposed)
// ---------------------------------------------------------------------------
__global__ __launch_bounds__(256) void proj_kernel(
    const unsigned short* __restrict__ ah, const unsigned short* __restrict__ al,
    const unsigned short* __restrict__ bh, const unsigned short* __restrict__ bl,
    const unsigned short* __restrict__ wparts,
    unsigned short* __restrict__ qhi, unsigned short* __restrict__ qlo,
    unsigned short* __restrict__ khi, unsigned short* __restrict__ vtout)
{
    const int mat = blockIdx.z;
    const unsigned short* __restrict__ XH = (mat == 0) ? ah : bh;
    const unsigned short* __restrict__ XL = (mat == 0) ? al : bl;
    const unsigned short* __restrict__ WH = wparts + mat * 2 * DIM * DIM;
    const unsigned short* __restrict__ WL = WH + DIM * DIM;

    const int tid  = threadIdx.x;
    const int wv   = tid >> 6;
    const int lane = tid & 63;
    const int c    = lane & 15;
    const int quad = lane >> 4;
    const int n0 = blockIdx.x * 64;
    const int j0 = blockIdx.y * 64 + wv * 16;

    f32x4 acc[4];
    #pragma unroll
    for (int nt = 0; nt < 4; ++nt) acc[nt] = (f32x4){0.f, 0.f, 0.f, 0.f};

    #pragma unroll
    for (int ki = 0; ki < 8; ++ki) {
        const int i0 = ki * 32 + quad * 8;
        bf16x8 wh = *(const bf16x8*)(WH + (j0 + c) * DIM + i0);
        bf16x8 wl = *(const bf16x8*)(WL + (j0 + c) * DIM + i0);
        #pragma unroll
        for (int nt = 0; nt < 4; ++nt) {
            const int row = (n0 + nt * 16 + c) * DIM + i0;
            bf16x8 xh = *(const bf16x8*)(XH + row);
            bf16x8 xl = *(const bf16x8*)(XL + row);
            acc[nt] = __builtin_amdgcn_mfma_f32_16x16x32_bf16(xh, wh, acc[nt], 0, 0, 0);
            acc[nt] = __builtin_amdgcn_mfma_f32_16x16x32_bf16(xl, wh, acc[nt], 0, 0, 0);
            acc[nt] = __builtin_amdgcn_mfma_f32_16x16x32_bf16(xh, wl, acc[nt], 0, 0, 0);
        }
    }

    // C/D layout: col = lane&15 (j), row = quad*4 + r (n)
    if (mat == 0) {
        #pragma unroll
        for (int nt = 0; nt < 4; ++nt)
            #pragma unroll
            for (int r = 0; r < 4; ++r) {
                const int idx = (n0 + nt * 16 + quad * 4 + r) * DIM + j0 + c;
                unsigned short h = f2bf(acc[nt][r]);
                qhi[idx] = h;
                qlo[idx] = f2bf(acc[nt][r] - bf2f(h));
            }
    } else if (mat == 1) {
        #pragma unroll
        for (int nt = 0; nt < 4; ++nt)
            #pragma unroll
            for (int r = 0; r < 4; ++r)
                khi[(n0 + nt * 16 + quad * 4 + r) * DIM + j0 + c] = f2bf(acc[nt][r]);
    } else {
        #pragma unroll
        for (int nt = 0; nt < 4; ++nt) {
            us4 p;
            #pragma unroll
            for (int r = 0; r < 4; ++r) p[r] = f2bf(acc[nt][r]);
            *(us4*)(vtout + (j0 + c) * NB + n0 + nt * 16 + quad * 4) = p;
        }
    }
}

// ---------------------------------------------------------------------------
// Fused attention, b-split for occupancy. Grid = (256 a-tiles, SPLIT b-ranges),
// 512 threads = 4 heads x 2 b-halves. SPLIT=4 -> 1024 blocks -> 4 blocks/CU
// x 8 waves = 32 waves/CU. LDS: pbuf unioned with numbuf (33.3 KB) -> 4/CU.
// Partials (per-head num[16][64] + den[16]) -> ws; reduce_kernel combines.
// ---------------------------------------------------------------------------
__global__ __launch_bounds__(512, 8) void attn_kernel(
    const unsigned short* __restrict__ qhg,
    const unsigned short* __restrict__ qlg,
    const unsigned short* __restrict__ kg,
    const unsigned short* __restrict__ vtg,
    const float* __restrict__ wg,
    const int* __restrict__ mg,
    float* __restrict__ pp)
{
    __shared__ __align__(16) char smem[SMEM_BYTES];
    unsigned short* pbuf = (unsigned short*)smem;            // [8][16*PSTR] = 18432 B
    float (*numbuf)[16][65] = (float (*)[16][65])smem;       // [8][16][65]  = 33280 B
    __shared__ float denbuf[8][16];

    const int tid  = threadIdx.x;
    const int wv   = tid >> 6;
    const int lane = tid & 63;
    const int c    = lane & 15;
    const int quad = lane >> 4;
    const int head = wv & 3;
    const int half = wv >> 2;
    const int t    = blockIdx.x;
    const int s    = blockIdx.y;
    const int SPLIT = gridDim.y;
    const int nit  = 32 / SPLIT;
    const int a0   = t * 16;

    bf16x8 qh[2], ql[2];
    #pragma unroll
    for (int ks = 0; ks < 2; ++ks) {
        qh[ks] = *(const bf16x8*)(qhg + (a0 + c) * DIM + head * DK + ks * 32 + quad * 8);
        ql[ks] = *(const bf16x8*)(qlg + (a0 + c) * DIM + head * DK + ks * 32 + quad * 8);
    }

    f32x4 num[4];
    #pragma unroll
    for (int nt = 0; nt < 4; ++nt) num[nt] = (f32x4){0.f, 0.f, 0.f, 0.f};
    float den = 0.0f;

    for (int it = s * nit; it < (s + 1) * nit; ++it) {
        const int b0 = (it * 2 + half) * 64;

        bf16x8 kf[4][2];
        #pragma unroll
        for (int bt = 0; bt < 4; ++bt)
            #pragma unroll
            for (int ks = 0; ks < 2; ++ks)
                kf[bt][ks] = *(const bf16x8*)(kg + (b0 + bt * 16 + c) * DIM + head * DK + ks * 32 + quad * 8);

        f32x4 wf[4];
        i32x4 mf[4];
        #pragma unroll
        for (int bt = 0; bt < 4; ++bt) {
            const size_t off = (size_t)(a0 + c) * NB + b0 + bt * 16 + quad * 4;
            wf[bt] = *(const f32x4*)(wg + off);
            mf[bt] = *(const i32x4*)(mg + off);
        }

        bf16x8 vf[4][2];
        #pragma unroll
        for (int nt = 0; nt < 4; ++nt)
            #pragma unroll
            for (int ks2 = 0; ks2 < 2; ++ks2)
                vf[nt][ks2] = *(const bf16x8*)(vtg + (head * DK + nt * 16 + c) * NB + b0 + ks2 * 32 + quad * 8);

        // S^T[b][a] = K·Q^T, 2-term q split
        f32x4 S[4];
        #pragma unroll
        for (int bt = 0; bt < 4; ++bt) {
            f32x4 sv = (f32x4){0.f, 0.f, 0.f, 0.f};
            sv = __builtin_amdgcn_mfma_f32_16x16x32_bf16(kf[bt][0], qh[0], sv, 0, 0, 0);
            sv = __builtin_amdgcn_mfma_f32_16x16x32_bf16(kf[bt][1], qh[1], sv, 0, 0, 0);
            sv = __builtin_amdgcn_mfma_f32_16x16x32_bf16(kf[bt][0], ql[0], sv, 0, 0, 0);
            sv = __builtin_amdgcn_mfma_f32_16x16x32_bf16(kf[bt][1], ql[1], sv, 0, 0, 0);
            S[bt] = sv;
        }

        // elementwise: lane holds (a = c, b = bt*16 + quad*4 + r)
        #pragma unroll
        for (int bt = 0; bt < 4; ++bt) {
            us4 p;
            #pragma unroll
            for (int r = 0; r < 4; ++r) {
                float tt = fmaf(S[bt][r], 0.125f, wf[bt][r]);
                tt = __builtin_amdgcn_fmed3f(tt, -10.0f, 10.0f);
                tt = mf[bt][r] ? tt : -10.0f;
                float e = exp2f(tt * 1.4426950408889634f);
                p[r] = f2bf(e);
                den += bf2f(p[r]);
            }
            *(us4*)(&pbuf[(size_t)wv * 16 * PSTR + c * PSTR + bt * 16 + quad * 4]) = p;
        }

        // PV from wave-private P (no barrier)
        bf16x8 pf[2];
        #pragma unroll
        for (int ks2 = 0; ks2 < 2; ++ks2)
            pf[ks2] = *(const bf16x8*)(&pbuf[(size_t)wv * 16 * PSTR + c * PSTR + ks2 * 32 + quad * 8]);
        #pragma unroll
        for (int nt = 0; nt < 4; ++nt) {
            num[nt] = __builtin_amdgcn_mfma_f32_16x16x32_bf16(pf[0], vf[nt][0], num[nt], 0, 0, 0);
            num[nt] = __builtin_amdgcn_mfma_f32_16x16x32_bf16(pf[1], vf[nt][1], num[nt], 0, 0, 0);
        }
    }

    // den across quads (same a = lane&15)
    den += __shfl_xor(den, 16, 64);
    den += __shfl_xor(den, 32, 64);
    if (lane < 16) denbuf[wv][lane] = den;

    __syncthreads();   // all pbuf reads done; union region becomes numbuf

    #pragma unroll
    for (int nt = 0; nt < 4; ++nt)
        #pragma unroll
        for (int r = 0; r < 4; ++r)
            numbuf[wv][quad * 4 + r][nt * 16 + c] = num[nt][r];
    __syncthreads();

    // partial write: per head h, num[16][64] (halves summed) + den[16]
    float* base = pp + (size_t)(t * SPLIT + s) * 4 * PBLK;
    for (int e = tid; e < 4 * 1024; e += 512) {
        const int h = e >> 10, idx = e & 1023;
        const int a = idx >> 6, dd = idx & 63;
        base[h * PBLK + idx] = numbuf[h][a][dd] + numbuf[h + 4][a][dd];
    }
    if (tid < 64) {
        const int h = tid >> 4, a = tid & 15;
        base[h * PBLK + 1024 + a] = denbuf[h][a] + denbuf[h + 4][a];
    }
}

// ---------------------------------------------------------------------------
// Combine SPLIT partials: out[a][dd] = 0.25 * sum_h (sum_s num)/(sum_s den).
// influence == 1.0 analytically (softmax rows sum to 1).
// ---------------------------------------------------------------------------
__global__ __launch_bounds__(256) void reduce_kernel(
    const float* __restrict__ pp, float* __restrict__ outp, int SPLIT)
{
    const int gid = blockIdx.x * 256 + threadIdx.x;   // 0 .. 262143
    const int a = gid >> 6, dd = gid & 63;
    const int t = a >> 4, ar = a & 15;
    float acc = 0.0f;
    #pragma unroll
    for (int h = 0; h < 4; ++h) {
        float n = 0.0f, d = 0.0f;
        for (int ss = 0; ss < SPLIT; ++ss) {
            const float* base = pp + (size_t)(t * SPLIT + ss) * 4 * PBLK + h * PBLK;
            n += base[ar * 64 + dd];
            d += base[1024 + ar];
        }
        acc += n / d;
    }
    outp[a * DK + dd] = 0.25f * acc;
    if (dd == 0) outp[NA * DK + a] = 1.0f;
}

extern "C" void kernel_launch(void* const* d_in, const int* in_sizes, int n_in,
                              void* d_out, int out_size, void* d_ws, size_t ws_size,
                              hipStream_t stream) {
    const float* a_z = (const float*)d_in[0];
    const float* bv  = (const float*)d_in[1];
    const int* mask  = (const int*)d_in[2];
    const float* wgt = (const float*)d_in[3];
    const float* Wq  = (const float*)d_in[4];
    const float* Wk  = (const float*)d_in[5];
    const float* Wv  = (const float*)d_in[6];
    float* out = (float*)d_out;

    const size_t NE = (size_t)NA * DIM;               // 1,048,576 elems
    unsigned short* qhi = (unsigned short*)d_ws;
    unsigned short* qlo = qhi + NE;
    unsigned short* khi = qlo + NE;
    unsigned short* vt  = khi + NE;
    unsigned short* ah  = vt  + NE;
    unsigned short* al  = ah  + NE;
    unsigned short* bh  = al  + NE;
    unsigned short* bl  = bh  + NE;
    unsigned short* wparts = bl + NE;                 // 6 * 65536 elems
    float* pp = (float*)(wparts + 6 * DIM * DIM);     // partials

    const size_t fixed = (char*)pp - (char*)d_ws;
    int SPLIT = 1;
    if (ws_size >= fixed + (size_t)256 * 4 * 4 * PBLK * 4) SPLIT = 4;
    else if (ws_size >= fixed + (size_t)256 * 2 * 4 * PBLK * 4) SPLIT = 2;

    split_kernel<<<dim3(1024, 5), 256, 0, stream>>>(a_z, bv, Wq, Wk, Wv,
                                                    ah, al, bh, bl, wparts);
    proj_kernel<<<dim3(64, 4, 3), 256, 0, stream>>>(ah, al, bh, bl, wparts,
                                                    qhi, qlo, khi, vt);
    attn_kernel<<<dim3(256, SPLIT), 512, 0, stream>>>(qhi, qlo, khi, vt, wgt, mask, pp);
    reduce_kernel<<<dim3(1024), 256, 0, stream>>>(pp, out, SPLIT);
}

// Round 5
// 358.525 us; speedup vs baseline: 1.3136x; 1.3136x over previous
//
#include <hip/hip_runtime.h>

#define NA 4096
#define NB 4096
#define DIM 256
#define DK 64
#define PSTR 72          // pbuf row stride (bf16 elements)
#define PBLK 1040        // partial block: 16*64 num + 16 den (floats)
// LDS union: pbuf 4*16*PSTR*2 = 9216 B; numbuf 4*16*65*4 = 16640 B -> 16640.
#define SMEM_BYTES 16640

typedef __attribute__((ext_vector_type(8))) short bf16x8;
typedef __attribute__((ext_vector_type(4))) float f32x4;
typedef __attribute__((ext_vector_type(4))) unsigned short us4;
typedef __attribute__((ext_vector_type(4))) int i32x4;

static __device__ __forceinline__ float bf2f(unsigned short u) {
    union { unsigned int u; float f; } x;
    x.u = ((unsigned int)u) << 16;
    return x.f;
}
static __device__ __forceinline__ unsigned short f2bf(float f) {
    union { float f; unsigned int u; } x;
    x.f = f;
    unsigned int r = x.u + 0x7fffu + ((x.u >> 16) & 1u);
    return (unsigned short)(r >> 16);
}

// ---------------------------------------------------------------------------
// Pre-split: fp32 -> bf16 hi + lo correction, fully coalesced elementwise.
// ---------------------------------------------------------------------------
__global__ __launch_bounds__(256) void split_kernel(
    const float* __restrict__ a_z, const float* __restrict__ bv_z,
    const float* __restrict__ Wq, const float* __restrict__ Wk,
    const float* __restrict__ Wv,
    unsigned short* __restrict__ ah, unsigned short* __restrict__ al,
    unsigned short* __restrict__ bh, unsigned short* __restrict__ bl,
    unsigned short* __restrict__ wparts)
{
    const int seg = blockIdx.y;
    const float* __restrict__ src;
    unsigned short *hi, *lo;
    int n;
    if (seg == 0)      { src = a_z;  hi = ah; lo = al; n = NA * DIM; }
    else if (seg == 1) { src = bv_z; hi = bh; lo = bl; n = NB * DIM; }
    else {
        src = (seg == 2) ? Wq : ((seg == 3) ? Wk : Wv);
        hi = wparts + (seg - 2) * 2 * DIM * DIM;
        lo = hi + DIM * DIM;
        n = DIM * DIM;
    }
    const int i = (blockIdx.x * 256 + threadIdx.x) * 4;
    if (i >= n) return;
    f32x4 v = *(const f32x4*)(src + i);
    us4 h4, l4;
    #pragma unroll
    for (int r = 0; r < 4; ++r) {
        unsigned short h = f2bf(v[r]);
        h4[r] = h;
        l4[r] = f2bf(v[r] - bf2f(h));
    }
    *(us4*)(hi + i) = h4;
    *(us4*)(lo + i) = l4;
}

// ---------------------------------------------------------------------------
// Projections from pre-split bf16, fp32-accurate via 3-term MFMA:
//   X·W^T ≈ xh·wh + xl·wh + xh·wl
// mat 0: q -> q_hi + q_lo ; mat 1: k -> k_hi ; mat 2: v -> vt (transposed)
// ---------------------------------------------------------------------------
__global__ __launch_bounds__(256) void proj_kernel(
    const unsigned short* __restrict__ ah, const unsigned short* __restrict__ al,
    const unsigned short* __restrict__ bh, const unsigned short* __restrict__ bl,
    const unsigned short* __restrict__ wparts,
    unsigned short* __restrict__ qhi, unsigned short* __restrict__ qlo,
    unsigned short* __restrict__ khi, unsigned short* __restrict__ vtout)
{
    const int mat = blockIdx.z;
    const unsigned short* __restrict__ XH = (mat == 0) ? ah : bh;
    const unsigned short* __restrict__ XL = (mat == 0) ? al : bl;
    const unsigned short* __restrict__ WH = wparts + mat * 2 * DIM * DIM;
    const unsigned short* __restrict__ WL = WH + DIM * DIM;

    const int tid  = threadIdx.x;
    const int wv   = tid >> 6;
    const int lane = tid & 63;
    const int c    = lane & 15;
    const int quad = lane >> 4;
    const int n0 = blockIdx.x * 64;
    const int j0 = blockIdx.y * 64 + wv * 16;

    f32x4 acc[4];
    #pragma unroll
    for (int nt = 0; nt < 4; ++nt) acc[nt] = (f32x4){0.f, 0.f, 0.f, 0.f};

    #pragma unroll
    for (int ki = 0; ki < 8; ++ki) {
        const int i0 = ki * 32 + quad * 8;
        bf16x8 wh = *(const bf16x8*)(WH + (j0 + c) * DIM + i0);
        bf16x8 wl = *(const bf16x8*)(WL + (j0 + c) * DIM + i0);
        #pragma unroll
        for (int nt = 0; nt < 4; ++nt) {
            const int row = (n0 + nt * 16 + c) * DIM + i0;
            bf16x8 xh = *(const bf16x8*)(XH + row);
            bf16x8 xl = *(const bf16x8*)(XL + row);
            acc[nt] = __builtin_amdgcn_mfma_f32_16x16x32_bf16(xh, wh, acc[nt], 0, 0, 0);
            acc[nt] = __builtin_amdgcn_mfma_f32_16x16x32_bf16(xl, wh, acc[nt], 0, 0, 0);
            acc[nt] = __builtin_amdgcn_mfma_f32_16x16x32_bf16(xh, wl, acc[nt], 0, 0, 0);
        }
    }

    // C/D layout: col = lane&15 (j), row = quad*4 + r (n)
    if (mat == 0) {
        #pragma unroll
        for (int nt = 0; nt < 4; ++nt)
            #pragma unroll
            for (int r = 0; r < 4; ++r) {
                const int idx = (n0 + nt * 16 + quad * 4 + r) * DIM + j0 + c;
                unsigned short h = f2bf(acc[nt][r]);
                qhi[idx] = h;
                qlo[idx] = f2bf(acc[nt][r] - bf2f(h));
            }
    } else if (mat == 1) {
        #pragma unroll
        for (int nt = 0; nt < 4; ++nt)
            #pragma unroll
            for (int r = 0; r < 4; ++r)
                khi[(n0 + nt * 16 + quad * 4 + r) * DIM + j0 + c] = f2bf(acc[nt][r]);
    } else {
        #pragma unroll
        for (int nt = 0; nt < 4; ++nt) {
            us4 p;
            #pragma unroll
            for (int r = 0; r < 4; ++r) p[r] = f2bf(acc[nt][r]);
            *(us4*)(vtout + (j0 + c) * NB + n0 + nt * 16 + quad * 4) = p;
        }
    }
}

// ---------------------------------------------------------------------------
// Fused attention. 256-thread blocks (4 waves = 4 heads), grid = (256 a-tiles,
// SPLIT b-ranges). Each iteration covers one 64-wide b tile.
// R4 lesson: do NOT cap registers for occupancy (spill = 570 MB scratch
// traffic). (256,4) caps at 128 VGPR/wave; natural alloc ~90-110 -> ~5-6
// waves/SIMD, LDS 16.6 KB is not limiting. Occupancy via 2048 blocks.
// ---------------------------------------------------------------------------
__global__ __launch_bounds__(256, 4) void attn_kernel(
    const unsigned short* __restrict__ qhg,
    const unsigned short* __restrict__ qlg,
    const unsigned short* __restrict__ kg,
    const unsigned short* __restrict__ vtg,
    const float* __restrict__ wg,
    const int* __restrict__ mg,
    float* __restrict__ pp)
{
    __shared__ __align__(16) char smem[SMEM_BYTES];
    unsigned short* pbuf = (unsigned short*)smem;            // [4][16*PSTR]
    float (*numbuf)[16][65] = (float (*)[16][65])smem;       // [4][16][65]
    __shared__ float denbuf[4][16];

    const int tid  = threadIdx.x;
    const int wv   = tid >> 6;      // 0..3 = head
    const int lane = tid & 63;
    const int c    = lane & 15;
    const int quad = lane >> 4;
    const int head = wv;
    const int t    = blockIdx.x;
    const int s    = blockIdx.y;
    const int SPLIT = gridDim.y;
    const int nit  = 64 / SPLIT;    // 64-wide b tiles per block
    const int a0   = t * 16;

    bf16x8 qh[2], ql[2];
    #pragma unroll
    for (int ks = 0; ks < 2; ++ks) {
        qh[ks] = *(const bf16x8*)(qhg + (a0 + c) * DIM + head * DK + ks * 32 + quad * 8);
        ql[ks] = *(const bf16x8*)(qlg + (a0 + c) * DIM + head * DK + ks * 32 + quad * 8);
    }

    f32x4 num[4];
    #pragma unroll
    for (int nt = 0; nt < 4; ++nt) num[nt] = (f32x4){0.f, 0.f, 0.f, 0.f};
    float den = 0.0f;

    for (int it = s * nit; it < (s + 1) * nit; ++it) {
        const int b0 = it * 64;

        bf16x8 kf[4][2];
        #pragma unroll
        for (int bt = 0; bt < 4; ++bt)
            #pragma unroll
            for (int ks = 0; ks < 2; ++ks)
                kf[bt][ks] = *(const bf16x8*)(kg + (b0 + bt * 16 + c) * DIM + head * DK + ks * 32 + quad * 8);

        f32x4 wf[4];
        i32x4 mf[4];
        #pragma unroll
        for (int bt = 0; bt < 4; ++bt) {
            const size_t off = (size_t)(a0 + c) * NB + b0 + bt * 16 + quad * 4;
            wf[bt] = *(const f32x4*)(wg + off);
            mf[bt] = *(const i32x4*)(mg + off);
        }

        bf16x8 vf[4][2];
        #pragma unroll
        for (int nt = 0; nt < 4; ++nt)
            #pragma unroll
            for (int ks2 = 0; ks2 < 2; ++ks2)
                vf[nt][ks2] = *(const bf16x8*)(vtg + (head * DK + nt * 16 + c) * NB + b0 + ks2 * 32 + quad * 8);

        // S^T[b][a] = K·Q^T, 2-term q split
        f32x4 S[4];
        #pragma unroll
        for (int bt = 0; bt < 4; ++bt) {
            f32x4 sv = (f32x4){0.f, 0.f, 0.f, 0.f};
            sv = __builtin_amdgcn_mfma_f32_16x16x32_bf16(kf[bt][0], qh[0], sv, 0, 0, 0);
            sv = __builtin_amdgcn_mfma_f32_16x16x32_bf16(kf[bt][1], qh[1], sv, 0, 0, 0);
            sv = __builtin_amdgcn_mfma_f32_16x16x32_bf16(kf[bt][0], ql[0], sv, 0, 0, 0);
            sv = __builtin_amdgcn_mfma_f32_16x16x32_bf16(kf[bt][1], ql[1], sv, 0, 0, 0);
            S[bt] = sv;
        }

        // elementwise: lane holds (a = c, b = bt*16 + quad*4 + r)
        #pragma unroll
        for (int bt = 0; bt < 4; ++bt) {
            us4 p;
            #pragma unroll
            for (int r = 0; r < 4; ++r) {
                float tt = fmaf(S[bt][r], 0.125f, wf[bt][r]);
                tt = __builtin_amdgcn_fmed3f(tt, -10.0f, 10.0f);
                tt = mf[bt][r] ? tt : -10.0f;
                float e = exp2f(tt * 1.4426950408889634f);
                p[r] = f2bf(e);
                den += bf2f(p[r]);
            }
            *(us4*)(&pbuf[(size_t)wv * 16 * PSTR + c * PSTR + bt * 16 + quad * 4]) = p;
        }

        // PV from wave-private P (no barrier)
        bf16x8 pf[2];
        #pragma unroll
        for (int ks2 = 0; ks2 < 2; ++ks2)
            pf[ks2] = *(const bf16x8*)(&pbuf[(size_t)wv * 16 * PSTR + c * PSTR + ks2 * 32 + quad * 8]);
        #pragma unroll
        for (int nt = 0; nt < 4; ++nt) {
            num[nt] = __builtin_amdgcn_mfma_f32_16x16x32_bf16(pf[0], vf[nt][0], num[nt], 0, 0, 0);
            num[nt] = __builtin_amdgcn_mfma_f32_16x16x32_bf16(pf[1], vf[nt][1], num[nt], 0, 0, 0);
        }
    }

    // den across quads (same a = lane&15)
    den += __shfl_xor(den, 16, 64);
    den += __shfl_xor(den, 32, 64);
    if (lane < 16) denbuf[wv][lane] = den;

    __syncthreads();   // all pbuf reads done; union region becomes numbuf

    #pragma unroll
    for (int nt = 0; nt < 4; ++nt)
        #pragma unroll
        for (int r = 0; r < 4; ++r)
            numbuf[wv][quad * 4 + r][nt * 16 + c] = num[nt][r];
    __syncthreads();

    // partial write: per head h, num[16][64] + den[16]
    float* base = pp + (size_t)(t * SPLIT + s) * 4 * PBLK;
    for (int e = tid; e < 4 * 1024; e += 256) {
        const int h = e >> 10, idx = e & 1023;
        const int a = idx >> 6, dd = idx & 63;
        base[h * PBLK + idx] = numbuf[h][a][dd];
    }
    if (tid < 64) {
        const int h = tid >> 4, a = tid & 15;
        base[h * PBLK + 1024 + a] = denbuf[h][a];
    }
}

// ---------------------------------------------------------------------------
// Combine SPLIT partials: out[a][dd] = 0.25 * sum_h (sum_s num)/(sum_s den).
// influence == 1.0 analytically (softmax rows sum to 1).
// ---------------------------------------------------------------------------
__global__ __launch_bounds__(256) void reduce_kernel(
    const float* __restrict__ pp, float* __restrict__ outp, int SPLIT)
{
    const int gid = blockIdx.x * 256 + threadIdx.x;   // 0 .. 262143
    const int a = gid >> 6, dd = gid & 63;
    const int t = a >> 4, ar = a & 15;
    float acc = 0.0f;
    #pragma unroll
    for (int h = 0; h < 4; ++h) {
        float n = 0.0f, d = 0.0f;
        for (int ss = 0; ss < SPLIT; ++ss) {
            const float* base = pp + (size_t)(t * SPLIT + ss) * 4 * PBLK + h * PBLK;
            n += base[ar * 64 + dd];
            d += base[1024 + ar];
        }
        acc += n / d;
    }
    outp[a * DK + dd] = 0.25f * acc;
    if (dd == 0) outp[NA * DK + a] = 1.0f;
}

extern "C" void kernel_launch(void* const* d_in, const int* in_sizes, int n_in,
                              void* d_out, int out_size, void* d_ws, size_t ws_size,
                              hipStream_t stream) {
    const float* a_z = (const float*)d_in[0];
    const float* bv  = (const float*)d_in[1];
    const int* mask  = (const int*)d_in[2];
    const float* wgt = (const float*)d_in[3];
    const float* Wq  = (const float*)d_in[4];
    const float* Wk  = (const float*)d_in[5];
    const float* Wv  = (const float*)d_in[6];
    float* out = (float*)d_out;

    const size_t NE = (size_t)NA * DIM;               // 1,048,576 elems
    unsigned short* qhi = (unsigned short*)d_ws;
    unsigned short* qlo = qhi + NE;
    unsigned short* khi = qlo + NE;
    unsigned short* vt  = khi + NE;
    unsigned short* ah  = vt  + NE;
    unsigned short* al  = ah  + NE;
    unsigned short* bh  = al  + NE;
    unsigned short* bl  = bh  + NE;
    unsigned short* wparts = bl + NE;                 // 6 * 65536 elems
    float* pp = (float*)(wparts + 6 * DIM * DIM);     // partials

    const size_t fixed = (char*)pp - (char*)d_ws;
    int SPLIT = 1;
    if (ws_size >= fixed + (size_t)256 * 8 * 4 * PBLK * 4) SPLIT = 8;
    else if (ws_size >= fixed + (size_t)256 * 4 * 4 * PBLK * 4) SPLIT = 4;
    else if (ws_size >= fixed + (size_t)256 * 2 * 4 * PBLK * 4) SPLIT = 2;

    split_kernel<<<dim3(1024, 5), 256, 0, stream>>>(a_z, bv, Wq, Wk, Wv,
                                                    ah, al, bh, bl, wparts);
    proj_kernel<<<dim3(64, 4, 3), 256, 0, stream>>>(ah, al, bh, bl, wparts,
                                                    qhi, qlo, khi, vt);
    attn_kernel<<<dim3(256, SPLIT), 256, 0, stream>>>(qhi, qlo, khi, vt, wgt, mask, pp);
    reduce_kernel<<<dim3(1024), 256, 0, stream>>>(pp, out, SPLIT);
}